// Round 1
// 410.401 us; speedup vs baseline: 1.0480x; 1.0480x over previous
//
#include <hip/hip_runtime.h>
#include <math.h>

// Sizes (fixed for this problem)
#define NB   16
#define NCIN 512
#define NL   1024
#define NCOUT 1024
#define NK   5
#define NDW  512
#define NHW  196
#define NP   208   // HW padded to 13 n-tiles of 16
#define NPK  224   // HW padded to 7 k-chunks of 32
#define NLG  1028  // NL + 4 zero guard rows at the front of each batch (for conv taps)

typedef unsigned short ushort_t;
typedef unsigned int uint_t;
typedef __attribute__((ext_vector_type(8))) short bf16x8;
typedef __attribute__((ext_vector_type(4))) float f32x4;

static __device__ __forceinline__ ushort_t f2bf(float f) {
  uint_t u = __builtin_bit_cast(uint_t, f);
  u += 0x7fff + ((u >> 16) & 1);  // round-to-nearest-even
  return (ushort_t)(u >> 16);
}
static __device__ __forceinline__ float bf2f(ushort_t u) {
  uint_t v = ((uint_t)u) << 16;
  return __builtin_bit_cast(float, v);
}

// raw barrier / counted vmcnt (avoid __syncthreads' vmcnt(0) drain)
#define BARM()    asm volatile("s_barrier" ::: "memory")
#define WAITVM8() asm volatile("s_waitcnt vmcnt(8)" ::: "memory")
#define WAITVM0() asm volatile("s_waitcnt vmcnt(0)" ::: "memory")

static __device__ __forceinline__ void gld16(const ushort_t* g, ushort_t* l) {
  __builtin_amdgcn_global_load_lds(
      (const __attribute__((address_space(1))) unsigned int*)g,
      (__attribute__((address_space(3))) unsigned int*)l, 16, 0, 0);
}

// ---------------------------------------------------------------------------
// K1: weight norm -> permuted bf16 weights, written in the conv kernel's
// interleaved row order: j = (c>>5)*64 + isB*32 + (c&31), where the original
// y-row is co = isB*512 + c.  This makes each wave's 64 B-rows contain 32
// matching (a,b) GLU column pairs.
// ---------------------------------------------------------------------------
__global__ __launch_bounds__(256) void wnorm_kernel(
    const float* __restrict__ v, const float* __restrict__ g,
    ushort_t* __restrict__ wperm) {
  const int o = blockIdx.x;
  const float* vr = v + (size_t)o * (NCIN * NK);
  float s = 0.f;
  for (int j = threadIdx.x; j < NCIN * NK; j += 256) {
    float t = vr[j];
    s += t * t;
  }
  for (int off = 32; off; off >>= 1) s += __shfl_down(s, off, 64);
  __shared__ float red[4];
  __shared__ float scale_s;
  const int wid = threadIdx.x >> 6;
  if ((threadIdx.x & 63) == 0) red[wid] = s;
  __syncthreads();
  if (threadIdx.x == 0) {
    float tot = red[0] + red[1] + red[2] + red[3];
    scale_s = g[o] / sqrtf(tot);
  }
  __syncthreads();
  const float scale = scale_s;
  const int isB = (o >= NDW) ? 1 : 0;
  const int c = o - isB * NDW;
  const int j = (c >> 5) * 64 + isB * 32 + (c & 31);
#pragma unroll
  for (int dk = 0; dk < NK; ++dk) {
    for (int ci = threadIdx.x; ci < NCIN; ci += 256) {
      wperm[((size_t)dk * NCOUT + j) * NCIN + ci] = f2bf(vr[ci * NK + dk] * scale);
    }
  }
}

// ---------------------------------------------------------------------------
// K2a: transpose + bf16 convert:  xT[b][l+4][ci] = bf16(x[b][ci][l])
// Stored with 4 zero guard rows per batch (stride NLG=1028 rows) so the conv
// kernel's shifted reads (l + dk - 4) never need a branch.
// ---------------------------------------------------------------------------
__global__ __launch_bounds__(256) void xpose_kernel(
    const float* __restrict__ x, ushort_t* __restrict__ xT) {
  const int b = blockIdx.z;
  const int ci0 = blockIdx.y * 64;
  const int l0 = blockIdx.x * 64;
  const int tid = threadIdx.x;
  __shared__ float t[64][65];
  const float* xb = x + ((size_t)b * NCIN + ci0) * NL + l0;
#pragma unroll
  for (int r = 0; r < 4; ++r) {
    int row = r * 16 + (tid >> 4);
    int col = (tid & 15) * 4;
    float4 v = *(const float4*)&xb[(size_t)row * NL + col];
    t[row][col + 0] = v.x; t[row][col + 1] = v.y;
    t[row][col + 2] = v.z; t[row][col + 3] = v.w;
  }
  __syncthreads();
  ushort_t* xo = xT + ((size_t)b * NLG + l0 + 4) * NCIN + ci0;
#pragma unroll
  for (int r = 0; r < 4; ++r) {
    int lrow = r * 16 + (tid >> 4);
    int cic = (tid & 15) * 4;
    ushort4 o4;
    o4.x = f2bf(t[cic + 0][lrow]);
    o4.y = f2bf(t[cic + 1][lrow]);
    o4.z = f2bf(t[cic + 2][lrow]);
    o4.w = f2bf(t[cic + 3][lrow]);
    *(ushort4*)&xo[(size_t)lrow * NCIN + cic] = o4;
  }
  // zero the 4 guard rows for this (b, ci-slice)
  if (blockIdx.x == 0) {
    for (int i = tid; i < 4 * 64; i += 256) {
      int rr = i >> 6, cc = i & 63;
      xT[((size_t)b * NLG + rr) * NCIN + ci0 + cc] = 0;
    }
  }
}

// ---------------------------------------------------------------------------
// K-prep: fc1_w / fc2_w -> bf16 (both [512][512], row-major, k=last dim)
// ---------------------------------------------------------------------------
__global__ __launch_bounds__(256) void wcvt_kernel(
    const float* __restrict__ w1, const float* __restrict__ w2,
    ushort_t* __restrict__ w1bf, ushort_t* __restrict__ w2bf) {
  const int i = (blockIdx.x * 256 + threadIdx.x) * 4;  // grid 256 -> covers 262144
  {
    float4 v = *(const float4*)&w1[i];
    ushort4 o; o.x = f2bf(v.x); o.y = f2bf(v.y); o.z = f2bf(v.z); o.w = f2bf(v.w);
    *(ushort4*)&w1bf[i] = o;
  }
  {
    float4 v = *(const float4*)&w2[i];
    ushort4 o; o.x = f2bf(v.x); o.y = f2bf(v.y); o.z = f2bf(v.z); o.w = f2bf(v.w);
    *(ushort4*)&w2bf[i] = o;
  }
}

// ---------------------------------------------------------------------------
// K-prep: feat transforms.
//  fThi/fTlo[b][p][a] : split-bf16 transpose of feat (rows p>=196 zeroed)
//  fbf[b][a][p']      : bf16 feat, p' padded to 224 with zeros
// grid (8 a-tiles, 16 b)
// ---------------------------------------------------------------------------
__global__ __launch_bounds__(256) void ftrans_kernel(
    const float* __restrict__ feat, ushort_t* __restrict__ fThi,
    ushort_t* __restrict__ fTlo, ushort_t* __restrict__ fbf) {
  const int b = blockIdx.y;
  const int a0 = blockIdx.x * 64;
  const int tid = threadIdx.x;
  __shared__ float t[64][200];

  const float* fb_ = feat + ((size_t)b * NDW + a0) * NHW;
#pragma unroll
  for (int pp = 0; pp < 16; ++pp) {
    int row = pp * 4 + (tid >> 6);
#pragma unroll
    for (int cc = 0; cc < 4; ++cc) {
      int col = cc * 64 + (tid & 63);
      if (col < NHW) t[row][col] = fb_[(size_t)row * NHW + col];
    }
  }
  __syncthreads();

  // fT writes: 208 p-rows x 64 a
  for (int pp = 0; pp < 13; ++pp) {
    int p = pp * 16 + (tid >> 4);
    int j = (tid & 15) * 4;
    ushort4 hi4, lo4;
#pragma unroll
    for (int k = 0; k < 4; ++k) {
      float v = (p < NHW) ? t[j + k][p] : 0.f;
      ushort_t h = f2bf(v);
      float lof = v - bf2f(h);
      ushort_t l = f2bf(lof);
      ((ushort_t*)&hi4)[k] = h;
      ((ushort_t*)&lo4)[k] = l;
    }
    size_t base = ((size_t)b * NP + p) * NDW + a0 + j;
    *(ushort4*)&fThi[base] = hi4;
    *(ushort4*)&fTlo[base] = lo4;
  }

  // fbf writes: 64 a-rows x 224 p
#pragma unroll
  for (int cc = 0; cc < 4; ++cc) {
    int col = cc * 64 + (tid & 63);
    if (col < NPK) {
#pragma unroll
      for (int rr = 0; rr < 16; ++rr) {
        int al = rr * 4 + (tid >> 6);
        float v = (col < NHW) ? t[al][col] : 0.f;
        fbf[((size_t)b * NDW + a0 + al) * NPK + col] = f2bf(v);
      }
    }
  }
}

// ---------------------------------------------------------------------------
// K2b: conv1d + bias + GLU via bf16 MFMA implicit GEMM — 256x256 phase-split
// schedule (T2 swizzle + T3/T4 counted-vmcnt prefetch + T5 setprio).
//
//  - 512 threads = 8 waves (2 M x 4 N); per-wave output 128 l x 64 y-rows.
//  - K = 2560 (5 dk x 512 ci) in 40 BK=64 tiles, double-buffered in LDS.
//  - Staging via global_load_lds dwordx4, LDS linear; bank-conflict-free
//    ds_read_b128 via XOR swizzle (byte ^= (row&7)<<4), applied by
//    pre-swizzling the per-lane GLOBAL source column (rule 21).
//  - Prefetch depth = 1 K-tile; main-loop wait is vmcnt(8), never 0.
//  - B rows interleave a/b GLU halves in 32-col groups so each wave holds
//    matching (a, gate) pairs: acc[mt][nt] (nt<2) pairs with acc[mt][nt+2].
// Writes hbfT[b][l][c] = bf16(h), c < 512.
// ---------------------------------------------------------------------------
__global__ __launch_bounds__(512, 2) void conv_glu_mfma(
    const ushort_t* __restrict__ xT, const ushort_t* __restrict__ wperm,
    const float* __restrict__ conv_b, ushort_t* __restrict__ hbfT) {
  const int bb = blockIdx.x >> 2;
  const int l0 = (blockIdx.x & 3) * 256;
  const int by = blockIdx.y;
  const int tid = threadIdx.x;
  const int wid = tid >> 6;
  const int lane = tid & 63;
  const int wm = wid >> 2;   // M half (0,1)
  const int wn = wid & 3;    // N quarter (0..3)
  const int quad = lane >> 4;
  const int l16 = lane & 15;
  const int sw = (l16 & 7) << 3;                        // read-side XOR (ushort units)
  const int csrc = ((lane & 7) ^ (lane >> 3)) << 3;     // staging source col (ushort units)

  __shared__ ushort_t sA[2][256][64];
  __shared__ ushort_t sB[2][256][64];

  f32x4 acc[8][4];
#pragma unroll
  for (int mt = 0; mt < 8; ++mt)
#pragma unroll
    for (int nt = 0; nt < 4; ++nt) acc[mt][nt] = (f32x4){0.f, 0.f, 0.f, 0.f};

  const ushort_t* gAbase = xT + (size_t)(bb * NLG + l0) * NCIN;
  const int r0 = wid * 8 + (lane >> 3);
  ushort_t* lA0 = &sA[0][0][0] + (wid * 64 + lane) * 8;
  ushort_t* lB0 = &sB[0][0][0] + (wid * 64 + lane) * 8;

  auto stage = [&](int tt, int s) {
    const int dk = tt >> 3;
    const int ci0 = (tt & 7) << 6;
    const ushort_t* gA = gAbase + (size_t)dk * NCIN + ci0 + csrc;
    const ushort_t* gB = wperm + ((size_t)dk * NCOUT + by * 256) * NCIN + ci0 + csrc;
    ushort_t* lA = lA0 + s * (256 * 64);
    ushort_t* lB = lB0 + s * (256 * 64);
#pragma unroll
    for (int c = 0; c < 4; ++c) {
      gld16(gA + (size_t)(r0 + c * 64) * NCIN, lA + c * 4096);
      gld16(gB + (size_t)(r0 + c * 64) * NCIN, lB + c * 4096);
    }
  };

  // prologue: stage tiles 0,1; wait tile 0 (tile 1 stays in flight)
  stage(0, 0);
  stage(1, 1);
  WAITVM8();
  BARM();

  for (int t = 0; t < 40; ++t) {
    const int s = t & 1;
    bf16x8 af[4][2], bfr[4][2];

    // ---- phase 0: read A(mth=0) + B(nt 0,1); MFMA quadrant (0,0)
#pragma unroll
    for (int mt = 0; mt < 4; ++mt)
#pragma unroll
      for (int ks = 0; ks < 2; ++ks)
        af[mt][ks] = *(const bf16x8*)&sA[s][wm * 128 + mt * 16 + l16]
                                        [(ks * 32 + quad * 8) ^ sw];
#pragma unroll
    for (int nt = 0; nt < 2; ++nt)
#pragma unroll
      for (int ks = 0; ks < 2; ++ks)
        bfr[nt][ks] = *(const bf16x8*)&sB[s][wn * 64 + nt * 16 + l16]
                                         [(ks * 32 + quad * 8) ^ sw];
    BARM();
    __builtin_amdgcn_s_setprio(1);
#pragma unroll
    for (int ks = 0; ks < 2; ++ks)
#pragma unroll
      for (int nt = 0; nt < 2; ++nt)
#pragma unroll
        for (int mt = 0; mt < 4; ++mt)
          acc[mt][nt] = __builtin_amdgcn_mfma_f32_16x16x32_bf16(
              af[mt][ks], bfr[nt][ks], acc[mt][nt], 0, 0, 0);
    __builtin_amdgcn_s_setprio(0);
    BARM();

    // ---- phase 1: read B(nt 2,3); MFMA quadrant (0,1)
#pragma unroll
    for (int nt = 2; nt < 4; ++nt)
#pragma unroll
      for (int ks = 0; ks < 2; ++ks)
        bfr[nt][ks] = *(const bf16x8*)&sB[s][wn * 64 + nt * 16 + l16]
                                         [(ks * 32 + quad * 8) ^ sw];
    BARM();
    __builtin_amdgcn_s_setprio(1);
#pragma unroll
    for (int ks = 0; ks < 2; ++ks)
#pragma unroll
      for (int nt = 2; nt < 4; ++nt)
#pragma unroll
        for (int mt = 0; mt < 4; ++mt)
          acc[mt][nt] = __builtin_amdgcn_mfma_f32_16x16x32_bf16(
              af[mt][ks], bfr[nt][ks], acc[mt][nt], 0, 0, 0);
    __builtin_amdgcn_s_setprio(0);
    BARM();

    // ---- phase 2: read A(mth=1); MFMA quadrant (1,0)  [B held in regs]
#pragma unroll
    for (int mt = 0; mt < 4; ++mt)
#pragma unroll
      for (int ks = 0; ks < 2; ++ks)
        af[mt][ks] = *(const bf16x8*)&sA[s][wm * 128 + (4 + mt) * 16 + l16]
                                        [(ks * 32 + quad * 8) ^ sw];
    BARM();
    __builtin_amdgcn_s_setprio(1);
#pragma unroll
    for (int ks = 0; ks < 2; ++ks)
#pragma unroll
      for (int nt = 0; nt < 2; ++nt)
#pragma unroll
        for (int mt = 0; mt < 4; ++mt)
          acc[4 + mt][nt] = __builtin_amdgcn_mfma_f32_16x16x32_bf16(
              af[mt][ks], bfr[nt][ks], acc[4 + mt][nt], 0, 0, 0);
    __builtin_amdgcn_s_setprio(0);
    BARM();
    // after this barrier no wave reads slot s again this tile -> safe to
    // overwrite it with the t+2 prefetch during phase 3.

    // ---- phase 3: issue prefetch of tile t+2 into slot s, MFMA (1,1)
    if (t < 38) stage(t + 2, s);
    __builtin_amdgcn_s_setprio(1);
#pragma unroll
    for (int ks = 0; ks < 2; ++ks)
#pragma unroll
      for (int nt = 2; nt < 4; ++nt)
#pragma unroll
        for (int mt = 0; mt < 4; ++mt)
          acc[4 + mt][nt] = __builtin_amdgcn_mfma_f32_16x16x32_bf16(
              af[mt][ks], bfr[nt][ks], acc[4 + mt][nt], 0, 0, 0);
    __builtin_amdgcn_s_setprio(0);

    // ---- tile end: ensure tile t+1 fully landed (8 newest = t+2 in flight)
    if (t < 39) {
      if (t < 38) { WAITVM8(); } else { WAITVM0(); }
      BARM();
    }
  }

  // epilogue: GLU, write hbfT[b][l][c] (c < 512)
#pragma unroll
  for (int nt = 0; nt < 2; ++nt) {
    const int c = by * 128 + wn * 32 + nt * 16 + l16;
    const float ba = conv_b[c];
    const float bg = conv_b[c + NDW];
#pragma unroll
    for (int mt = 0; mt < 8; ++mt) {
      const int lg = l0 + wm * 128 + mt * 16 + quad * 4;
      ushort_t* ho = hbfT + ((size_t)bb * NL + lg) * NDW + c;
#pragma unroll
      for (int r = 0; r < 4; ++r) {
        float aa = acc[mt][nt][r] + ba;
        float gg = acc[mt][nt + 2][r] + bg;
        float hv = aa * (1.f / (1.f + __expf(-gg)));
        ho[(size_t)r * NDW] = f2bf(hv);
      }
    }
  }
}

// ---------------------------------------------------------------------------
// K3: fc1 MFMA.  q[l][a] = sum_c hbfT[l][c]*w1bf[a][c] + b[a] + we[l][a]
// Writes split q: qhi/qlo bf16 [b][l][a].
// ---------------------------------------------------------------------------
__global__ __launch_bounds__(256, 2) void fc1_mfma(
    const ushort_t* __restrict__ hbfT, const ushort_t* __restrict__ w1bf,
    const float* __restrict__ fb, const float* __restrict__ we,
    ushort_t* __restrict__ qhi, ushort_t* __restrict__ qlo) {
  const int b  = blockIdx.z;
  const int a0 = blockIdx.y * 128;
  const int l0 = blockIdx.x * 128;
  const int tid = threadIdx.x;
  const int wid = tid >> 6;
  const int lane = tid & 63;
  const int wl = wid & 1;
  const int wc = wid >> 1;
  const int quad = lane >> 4;
  const int l16 = lane & 15;

  __shared__ ushort_t la[128][72];
  __shared__ ushort_t lb[128][72];

  f32x4 acc[4][4];
#pragma unroll
  for (int mt = 0; mt < 4; ++mt)
#pragma unroll
    for (int nt = 0; nt < 4; ++nt) acc[mt][nt] = (f32x4){0.f, 0.f, 0.f, 0.f};

  const ushort_t* hb = hbfT + (size_t)b * NL * NDW;

  for (int c0 = 0; c0 < NDW; c0 += 64) {
    __syncthreads();
#pragma unroll
    for (int it = 0; it < 4; ++it) {
      int t = tid + it * 256;
      int r = t >> 3, seg = t & 7;
      *(uint4*)&la[r][seg * 8] = *(const uint4*)(hb + (size_t)(l0 + r) * NDW + c0 + seg * 8);
    }
#pragma unroll
    for (int it = 0; it < 4; ++it) {
      int t = tid + it * 256;
      int r = t >> 3, seg = t & 7;
      *(uint4*)&lb[r][seg * 8] = *(const uint4*)(w1bf + (size_t)(a0 + r) * NDW + c0 + seg * 8);
    }
    __syncthreads();
#pragma unroll
    for (int ks = 0; ks < 2; ++ks) {
      bf16x8 af[4];
#pragma unroll
      for (int mt = 0; mt < 4; ++mt)
        af[mt] = *(const bf16x8*)&la[wl * 64 + mt * 16 + l16][ks * 32 + quad * 8];
#pragma unroll
      for (int nt = 0; nt < 4; ++nt) {
        bf16x8 bf = *(const bf16x8*)&lb[wc * 64 + nt * 16 + l16][ks * 32 + quad * 8];
#pragma unroll
        for (int mt = 0; mt < 4; ++mt)
          acc[mt][nt] = __builtin_amdgcn_mfma_f32_16x16x32_bf16(af[mt], bf, acc[mt][nt], 0, 0, 0);
      }
    }
  }

#pragma unroll
  for (int nt = 0; nt < 4; ++nt) {
    const int a = a0 + wc * 64 + nt * 16 + l16;
    const float bias = fb[a];
#pragma unroll
    for (int mt = 0; mt < 4; ++mt) {
      const int l = l0 + wl * 64 + mt * 16 + quad * 4;
#pragma unroll
      for (int r = 0; r < 4; ++r) {
        size_t idx = ((size_t)b * NL + l + r) * NDW + a;
        float qv = acc[mt][nt][r] + bias + we[idx];
        ushort_t h = f2bf(qv);
        float lof = qv - bf2f(h);
        qhi[idx] = h;
        qlo[idx] = f2bf(lof);
      }
    }
  }
}

// ---------------------------------------------------------------------------
// K4a: scores + softmax, 3-pass split-bf16 MFMA.
//   S[l][p] = qh·fh + ql·fh + qh·fl  (fp32 acc), softmax over p -> out_attn fp32
// Block: 64 l x 208 p; 4 waves, wave = 16 l (1 m-tile) x 13 n-tiles.
// grid (16 l-tiles, 16 b)
// ---------------------------------------------------------------------------
__global__ __launch_bounds__(256) void score_softmax(
    const ushort_t* __restrict__ qhi, const ushort_t* __restrict__ qlo,
    const ushort_t* __restrict__ fThi, const ushort_t* __restrict__ fTlo,
    float* __restrict__ out_attn) {
  const int b  = blockIdx.y;
  const int l0 = blockIdx.x * 64;
  const int tid = threadIdx.x;
  const int wid = tid >> 6;
  const int lane = tid & 63;
  const int quad = lane >> 4;
  const int l16 = lane & 15;

  __shared__ ushort_t qh[64][36], ql[64][36];
  __shared__ ushort_t fh[208][36], fl[208][36];

  f32x4 acc[13];
#pragma unroll
  for (int nt = 0; nt < 13; ++nt) acc[nt] = (f32x4){0.f, 0.f, 0.f, 0.f};

  for (int kc = 0; kc < 16; ++kc) {
    const int a0 = kc * 32;
    __syncthreads();
    {
      int r = tid >> 2, seg = tid & 3;
      size_t src = ((size_t)b * NL + l0 + r) * NDW + a0 + seg * 8;
      *(uint4*)&qh[r][seg * 8] = *(const uint4*)(qhi + src);
      *(uint4*)&ql[r][seg * 8] = *(const uint4*)(qlo + src);
#pragma unroll
      for (int it = 0; it < 4; ++it) {
        int row = it * 64 + (tid >> 2);
        if (row < NP) {
          size_t fsrc = ((size_t)b * NP + row) * NDW + a0 + seg * 8;
          *(uint4*)&fh[row][seg * 8] = *(const uint4*)(fThi + fsrc);
          *(uint4*)&fl[row][seg * 8] = *(const uint4*)(fTlo + fsrc);
        }
      }
    }
    __syncthreads();
    bf16x8 ah = *(const bf16x8*)&qh[wid * 16 + l16][quad * 8];
    bf16x8 al = *(const bf16x8*)&ql[wid * 16 + l16][quad * 8];
#pragma unroll
    for (int nt = 0; nt < 13; ++nt) {
      bf16x8 bh = *(const bf16x8*)&fh[nt * 16 + l16][quad * 8];
      bf16x8 bl = *(const bf16x8*)&fl[nt * 16 + l16][quad * 8];
      acc[nt] = __builtin_amdgcn_mfma_f32_16x16x32_bf16(ah, bh, acc[nt], 0, 0, 0);
      acc[nt] = __builtin_amdgcn_mfma_f32_16x16x32_bf16(al, bh, acc[nt], 0, 0, 0);
      acc[nt] = __builtin_amdgcn_mfma_f32_16x16x32_bf16(ah, bl, acc[nt], 0, 0, 0);
    }
  }

  // softmax per row; D layout: row = quad*4 + r, col p = nt*16 + l16
  const bool v12 = (l16 < 4);  // nt=12 valid only for p=192+l16 < 196
#pragma unroll
  for (int r = 0; r < 4; ++r) {
    float mx = -1e30f;
#pragma unroll
    for (int nt = 0; nt < 12; ++nt) mx = fmaxf(mx, acc[nt][r]);
    if (v12) mx = fmaxf(mx, acc[12][r]);
#pragma unroll
    for (int off = 1; off < 16; off <<= 1) mx = fmaxf(mx, __shfl_xor(mx, off, 16));
    float ex[13];
    float sum = 0.f;
#pragma unroll
    for (int nt = 0; nt < 12; ++nt) { ex[nt] = __expf(acc[nt][r] - mx); sum += ex[nt]; }
    ex[12] = v12 ? __expf(acc[12][r] - mx) : 0.f;
    sum += ex[12];
#pragma unroll
    for (int off = 1; off < 16; off <<= 1) sum += __shfl_xor(sum, off, 16);
    const float inv = 1.f / sum;
    const int l = l0 + wid * 16 + quad * 4 + r;
    float* ao = out_attn + ((size_t)b * NL + l) * NHW;
#pragma unroll
    for (int nt = 0; nt < 13; ++nt) {
      int p = nt * 16 + l16;
      if (p < NHW) ao[p] = ex[nt] * inv;
    }
  }
}

// ---------------------------------------------------------------------------
// K4b: ctx MFMA.  ctx[l][a] = sum_p attn[l][p] * fbf[a][p]   (K padded to 224)
// A staged from out_attn fp32 (cvt to bf16), B from fbf.  Writes ctx_bf[b][l][a].
// ---------------------------------------------------------------------------
__global__ __launch_bounds__(256, 2) void ctx_mfma(
    const float* __restrict__ attn, const ushort_t* __restrict__ fbf,
    ushort_t* __restrict__ ctx_bf) {
  const int b  = blockIdx.z;
  const int a0 = blockIdx.y * 128;
  const int l0 = blockIdx.x * 128;
  const int tid = threadIdx.x;
  const int wid = tid >> 6;
  const int lane = tid & 63;
  const int wl = wid & 1;
  const int wc = wid >> 1;
  const int quad = lane >> 4;
  const int l16 = lane & 15;

  __shared__ ushort_t la[128][36];
  __shared__ ushort_t lb[128][36];

  f32x4 acc[4][4];
#pragma unroll
  for (int mt = 0; mt < 4; ++mt)
#pragma unroll
    for (int nt = 0; nt < 4; ++nt) acc[mt][nt] = (f32x4){0.f, 0.f, 0.f, 0.f};

  for (int kc = 0; kc < 7; ++kc) {
    const int p0 = kc * 32;
    __syncthreads();
#pragma unroll
    for (int it = 0; it < 2; ++it) {
      int r = it * 64 + (tid >> 2), seg = tid & 3;
      int pb = p0 + seg * 8;
      const float* src = attn + ((size_t)b * NL + l0 + r) * NHW + pb;
      ushort4 o[2];
      if (pb + 7 < NHW) {
        float4 v0 = *(const float4*)src;
        float4 v1 = *(const float4*)(src + 4);
        o[0].x = f2bf(v0.x); o[0].y = f2bf(v0.y); o[0].z = f2bf(v0.z); o[0].w = f2bf(v0.w);
        o[1].x = f2bf(v1.x); o[1].y = f2bf(v1.y); o[1].z = f2bf(v1.z); o[1].w = f2bf(v1.w);
      } else {
#pragma unroll
        for (int k = 0; k < 8; ++k) {
          float v = (pb + k < NHW) ? src[k] : 0.f;
          ((ushort_t*)o)[k] = f2bf(v);
        }
      }
      *(uint4*)&la[r][seg * 8] = *(uint4*)o;
      // B tile: fbf rows a
      const ushort_t* fsrc = fbf + ((size_t)b * NDW + a0 + r) * NPK + pb;
      *(uint4*)&lb[r][seg * 8] = *(const uint4*)fsrc;
    }
    __syncthreads();
    bf16x8 af[4];
#pragma unroll
    for (int mt = 0; mt < 4; ++mt)
      af[mt] = *(const bf16x8*)&la[wl * 64 + mt * 16 + l16][quad * 8];
#pragma unroll
    for (int nt = 0; nt < 4; ++nt) {
      bf16x8 bf = *(const bf16x8*)&lb[wc * 64 + nt * 16 + l16][quad * 8];
#pragma unroll
      for (int mt = 0; mt < 4; ++mt)
        acc[mt][nt] = __builtin_amdgcn_mfma_f32_16x16x32_bf16(af[mt], bf, acc[mt][nt], 0, 0, 0);
    }
  }

#pragma unroll
  for (int nt = 0; nt < 4; ++nt) {
    const int a = a0 + wc * 64 + nt * 16 + l16;
#pragma unroll
    for (int mt = 0; mt < 4; ++mt) {
      const int l = l0 + wl * 64 + mt * 16 + quad * 4;
#pragma unroll
      for (int r = 0; r < 4; ++r)
        ctx_bf[((size_t)b * NL + l + r) * NDW + a] = f2bf(acc[mt][nt][r]);
    }
  }
}

// ---------------------------------------------------------------------------
// K5: fc2 MFMA.  out[c][l] = sum_a w2bf[c][a]*ctx_bf[l][a] + fb2[c] + h + x
// M = c (A side), N = l (B side).
// ---------------------------------------------------------------------------
__global__ __launch_bounds__(256, 2) void fc2_mfma(
    const ushort_t* __restrict__ w2bf, const ushort_t* __restrict__ ctx_bf,
    const float* __restrict__ fb2, const ushort_t* __restrict__ hbfT,
    const float* __restrict__ x, float* __restrict__ out0) {
  const int b  = blockIdx.z;
  const int c0 = blockIdx.y * 128;
  const int l0 = blockIdx.x * 128;
  const int tid = threadIdx.x;
  const int wid = tid >> 6;
  const int lane = tid & 63;
  const int wl = wid & 1;   // c sub-tile
  const int wc = wid >> 1;  // l sub-tile
  const int quad = lane >> 4;
  const int l16 = lane & 15;

  __shared__ ushort_t la[128][72];
  __shared__ ushort_t lb[128][72];

  f32x4 acc[4][4];
#pragma unroll
  for (int mt = 0; mt < 4; ++mt)
#pragma unroll
    for (int nt = 0; nt < 4; ++nt) acc[mt][nt] = (f32x4){0.f, 0.f, 0.f, 0.f};

  for (int a0 = 0; a0 < NDW; a0 += 64) {
    __syncthreads();
#pragma unroll
    for (int it = 0; it < 4; ++it) {
      int t = tid + it * 256;
      int r = t >> 3, seg = t & 7;
      *(uint4*)&la[r][seg * 8] = *(const uint4*)(w2bf + (size_t)(c0 + r) * NDW + a0 + seg * 8);
    }
#pragma unroll
    for (int it = 0; it < 4; ++it) {
      int t = tid + it * 256;
      int r = t >> 3, seg = t & 7;
      *(uint4*)&lb[r][seg * 8] =
          *(const uint4*)(ctx_bf + ((size_t)b * NL + l0 + r) * NDW + a0 + seg * 8);
    }
    __syncthreads();
#pragma unroll
    for (int ks = 0; ks < 2; ++ks) {
      bf16x8 af[4];
#pragma unroll
      for (int mt = 0; mt < 4; ++mt)
        af[mt] = *(const bf16x8*)&la[wl * 64 + mt * 16 + l16][ks * 32 + quad * 8];
#pragma unroll
      for (int nt = 0; nt < 4; ++nt) {
        bf16x8 bf = *(const bf16x8*)&lb[wc * 64 + nt * 16 + l16][ks * 32 + quad * 8];
#pragma unroll
        for (int mt = 0; mt < 4; ++mt)
          acc[mt][nt] = __builtin_amdgcn_mfma_f32_16x16x32_bf16(af[mt], bf, acc[mt][nt], 0, 0, 0);
      }
    }
  }

  // epilogue: row = c, col = l
#pragma unroll
  for (int mt = 0; mt < 4; ++mt) {
    const int cb = c0 + wl * 64 + mt * 16 + quad * 4;
    float4 bias4 = *(const float4*)&fb2[cb];
#pragma unroll
    for (int nt = 0; nt < 4; ++nt) {
      const int l = l0 + wc * 64 + nt * 16 + l16;
      ushort4 h4 = *(const ushort4*)&hbfT[((size_t)b * NL + l) * NDW + cb];
      const float bias[4] = {bias4.x, bias4.y, bias4.z, bias4.w};
      const ushort_t hs[4] = {h4.x, h4.y, h4.z, h4.w};
#pragma unroll
      for (int r = 0; r < 4; ++r) {
        size_t idx = ((size_t)b * NDW + cb + r) * NL + l;
        out0[idx] = acc[mt][nt][r] + bias[r] + bf2f(hs[r]) + x[idx];
      }
    }
  }
}

// ---------------------------------------------------------------------------
extern "C" void kernel_launch(void* const* d_in, const int* in_sizes, int n_in,
                              void* d_out, int out_size, void* d_ws, size_t ws_size,
                              hipStream_t stream) {
  const float* x      = (const float*)d_in[0];
  const float* we     = (const float*)d_in[1];
  const float* img    = (const float*)d_in[2];
  const float* conv_v = (const float*)d_in[4];
  const float* conv_g = (const float*)d_in[5];
  const float* conv_b = (const float*)d_in[6];
  const float* fc1_w  = (const float*)d_in[7];
  const float* fc1_b  = (const float*)d_in[8];
  const float* fc2_w  = (const float*)d_in[9];
  const float* fc2_b  = (const float*)d_in[10];

  float* out0     = (float*)d_out;          // (16,512,1024)
  float* out_we   = out0 + 8388608;         // (16,1024,512)
  float* out_img  = out_we + 8388608;       // (16,512,14,14)
  float* out_attn = out_img + 1605632;      // (16,1024,196)

  // Workspace layout (ushort units). Total 61.9 MB < 77.6 MB proven available.
  ushort_t* wsu = (ushort_t*)d_ws;
  ushort_t* qhi   = wsu;                    // 8,388,608   [fc1 -> score]
  ushort_t* qlo   = wsu + 8388608;          // 8,388,608   [fc1 -> score]
  ushort_t* wperm = wsu;                    // 2,621,440   [phase A alias of qhi]
  ushort_t* xT    = wsu + 2621440;          // 8,421,376 (16x1028x512) [phase A alias, ends 11,042,816]
  ushort_t* ctx_b = wsu;                    // 8,388,608   [ctx -> fc2; qhi dead]
  ushort_t* hbfT  = wsu + 16777216;         // 8,388,608   [conv -> fc2]
  ushort_t* w1bf  = wsu + 25165824;         // 262,144
  ushort_t* w2bf  = wsu + 25165824 + 262144;  // 262,144
  ushort_t* fThi  = wsu + 25690112;         // 1,703,936
  ushort_t* fTlo  = wsu + 27394048;         // 1,703,936
  ushort_t* fbf   = wsu + 29097984;         // 1,835,008  -> ends 30,932,992

  wnorm_kernel<<<dim3(NCOUT), 256, 0, stream>>>(conv_v, conv_g, wperm);
  xpose_kernel<<<dim3(16, 8, NB), 256, 0, stream>>>(x, xT);
  wcvt_kernel<<<dim3(256), 256, 0, stream>>>(fc1_w, fc2_w, w1bf, w2bf);
  ftrans_kernel<<<dim3(8, NB), 256, 0, stream>>>(img, fThi, fTlo, fbf);

  conv_glu_mfma<<<dim3(64, 4), 512, 0, stream>>>(xT, wperm, conv_b, hbfT);
  fc1_mfma<<<dim3(8, 4, NB), 256, 0, stream>>>(hbfT, w1bf, fc1_b, we, qhi, qlo);
  score_softmax<<<dim3(16, NB), 256, 0, stream>>>(qhi, qlo, fThi, fTlo, out_attn);
  ctx_mfma<<<dim3(8, 4, NB), 256, 0, stream>>>(out_attn, fbf, ctx_b);
  fc2_mfma<<<dim3(8, 4, NB), 256, 0, stream>>>(w2bf, ctx_b, fc2_b, hbfT, x, out0);

  hipMemcpyAsync(out_we, we, (size_t)8388608 * sizeof(float),
                 hipMemcpyDeviceToDevice, stream);
  hipMemcpyAsync(out_img, img, (size_t)1605632 * sizeof(float),
                 hipMemcpyDeviceToDevice, stream);
}